// Round 6
// baseline (436.858 us; speedup 1.0000x reference)
//
#include <hip/hip_runtime.h>

#define BATCH 32
#define NPTS  1024
#define NFEAT 256
#define NPROP 256
#define NSAMP 16

// flat output offsets (floats), in reference tuple order
#define O_OBJ    0
#define O_CENTER 16384
#define O_HS     40960
#define O_HRN    139264
#define O_HR     237568
#define O_SS     335872
#define O_SRN    483328
#define O_SR     925696
#define O_SEM    1368064
#define O_NX     1515520
#define O_INDS   1540096

typedef __attribute__((ext_vector_type(8))) short bf16x8;
typedef __attribute__((ext_vector_type(8))) unsigned short u16x8;
typedef __attribute__((ext_vector_type(2))) float f32x2;
typedef __attribute__((ext_vector_type(16))) float f32x16;

__device__ __forceinline__ unsigned short f2bf(float f) {
  unsigned u = __builtin_bit_cast(unsigned, f);
  u += 0x7fffu + ((u >> 16) & 1u);   // RNE to bf16
  return (unsigned short)(u >> 16);
}

__device__ __forceinline__ unsigned long long umax64(unsigned long long a,
                                                     unsigned long long b) {
  return a > b ? a : b;   // v_cmp_gt_u64 + 2x cndmask
}

// one cross-lane max step on a 64-bit key (hi=dist bits, lo=1023-idx)
template<int CTRL>
__device__ __forceinline__ unsigned long long dpp_max_u64(unsigned long long v) {
  int lo = (int)(unsigned)v;
  int hi = (int)(v >> 32);
  int lo2 = __builtin_amdgcn_update_dpp(lo, lo, CTRL, 0xf, 0xf, false);
  int hi2 = __builtin_amdgcn_update_dpp(hi, hi, CTRL, 0xf, 0xf, false);
  unsigned long long o = (((unsigned long long)(unsigned)hi2) << 32) | (unsigned)lo2;
  return umax64(v, o);
}

// ---------------------------------------------------------------------------
// Kernel 1: FPS — one wave per batch, 16 pts/lane in registers.
// Single-pass argmax: key = (bits(d)<<32) | (1023-k); d>=0 so fp bits are
// order-monotone; max key == (max d, min k) == jnp.argmax first-max.
// Packed f32x2 distances (IEEE per lane, contract off) for issue width.
// ---------------------------------------------------------------------------
__global__ __launch_bounds__(64) void fps_kernel(
    const float* __restrict__ xyz,
    float* __restrict__ o_nx,
    float* __restrict__ o_inds)
{
#pragma clang fp contract(off)
  __shared__ float sxyz[NPTS*3];
  __shared__ int   sInd[NPROP];

  const int b = blockIdx.x;
  const int t = threadIdx.x;              // 0..63
  const float* xb = xyz + b * NPTS * 3;
  for (int i = t; i < NPTS*3; i += 64) sxyz[i] = xb[i];
  __syncthreads();

  // pair a holds points k0 = t+128a (comp 0) and k1 = k0+64 (comp 1)
  f32x2 px[8], py[8], pz[8], dd[8];
  int loc[16];                            // 1023 - k, constant per slot
#pragma unroll
  for (int a = 0; a < 8; ++a) {
    int k0 = t + 128*a, k1 = k0 + 64;
    px[a] = (f32x2){sxyz[k0*3+0], sxyz[k1*3+0]};
    py[a] = (f32x2){sxyz[k0*3+1], sxyz[k1*3+1]};
    pz[a] = (f32x2){sxyz[k0*3+2], sxyz[k1*3+2]};
    dd[a] = (f32x2){1e10f, 1e10f};
    loc[2*a]   = 1023 - k0;
    loc[2*a+1] = 1023 - k1;
  }

  int last = 0;
  for (int it = 1; it < NPROP; ++it) {
    float lx = sxyz[last*3+0], ly = sxyz[last*3+1], lz = sxyz[last*3+2];
    f32x2 vlx = (f32x2){lx, lx}, vly = (f32x2){ly, ly}, vlz = (f32x2){lz, lz};
#pragma unroll
    for (int a = 0; a < 8; ++a) {
      f32x2 dx = px[a] - vlx;
      f32x2 dy = py[a] - vly;
      f32x2 dz = pz[a] - vlz;
      f32x2 d  = dx*dx + dy*dy + dz*dz;   // contract off: mul,mul,mul,add,add
      dd[a] = __builtin_elementwise_min(dd[a], d);
    }
    // build 64-bit keys (hi = dist bits, lo = precomputed 1023-k)
    unsigned long long key[16];
#pragma unroll
    for (int a = 0; a < 8; ++a) {
      float d0 = dd[a][0], d1 = dd[a][1];
      key[2*a]   = (((unsigned long long)__builtin_bit_cast(unsigned, d0)) << 32)
                   | (unsigned)loc[2*a];
      key[2*a+1] = (((unsigned long long)__builtin_bit_cast(unsigned, d1)) << 32)
                   | (unsigned)loc[2*a+1];
    }
    // in-lane max tree (depth 4)
#pragma unroll
    for (int off = 1; off < 16; off <<= 1)
#pragma unroll
      for (int i = 0; i < 16; i += 2*off)
        key[i] = umax64(key[i], key[i+off]);
    // cross-lane max -> lane 63 (single chain)
    unsigned long long kk = key[0];
    kk = dpp_max_u64<0x111>(kk);   // row_shr:1
    kk = dpp_max_u64<0x112>(kk);   // row_shr:2
    kk = dpp_max_u64<0x114>(kk);   // row_shr:4
    kk = dpp_max_u64<0x118>(kk);   // row_shr:8
    kk = dpp_max_u64<0x142>(kk);   // row_bcast:15
    kk = dpp_max_u64<0x143>(kk);   // row_bcast:31
    int lo63 = __builtin_amdgcn_readlane((int)(unsigned)kk, 63);
    last = 1023 - lo63;
    if (t == 0) sInd[it] = last;
  }
  if (t == 0) sInd[0] = 0;
  __syncthreads();

  for (int s = t; s < NPROP; s += 64) {
    int ind = sInd[s];
    o_inds[b*NPROP + s] = (float)ind;
    float* nx = o_nx + (b*NPROP + s)*3;
    nx[0] = sxyz[ind*3+0]; nx[1] = sxyz[ind*3+1]; nx[2] = sxyz[ind*3+2];
  }
}

// ---------------------------------------------------------------------------
// Kernel 1b: ball query — one wave per proposal (unchanged; exact).
// ---------------------------------------------------------------------------
__global__ __launch_bounds__(256) void bq_kernel(
    const float* __restrict__ xyz,
    const float* __restrict__ o_nx,
    int* __restrict__ ws_idx)
{
  const int lane = threadIdx.x & 63;
  const int wid  = threadIdx.x >> 6;
  const int bp   = blockIdx.x * 4 + wid;
  const int b    = bp >> 8;
  const float* xb = xyz + b * NPTS * 3;

  const float qx = o_nx[bp*3+0];
  const float qy = o_nx[bp*3+1];
  const float qz = o_nx[bp*3+2];

  const int k0 = lane * 16;
  unsigned mask = 0u;
#pragma unroll
  for (int j = 0; j < 16; ++j) {
    int k = k0 + j;
    float dx = __fsub_rn(qx, xb[k*3+0]);
    float dy = __fsub_rn(qy, xb[k*3+1]);
    float dz = __fsub_rn(qz, xb[k*3+2]);
    float d2 = __fadd_rn(__fadd_rn(__fmul_rn(dx,dx), __fmul_rn(dy,dy)), __fmul_rn(dz,dz));
    if (d2 < 0.09f) mask |= (1u << j);
  }
  int cnt  = __popc(mask);
  int incl = cnt;
#pragma unroll
  for (int ofs = 1; ofs < 64; ofs <<= 1) {
    int v = __shfl_up(incl, ofs);
    if (lane >= ofs) incl += v;
  }
  int start = incl - cnt;
  int total = __shfl(incl, 63);

  int fc = mask ? (k0 + __ffs(mask) - 1) : 0x7fffffff;
#pragma unroll
  for (int m = 32; m >= 1; m >>= 1) fc = min(fc, __shfl_xor(fc, m));
  int first = (total > 0) ? fc : (NPTS - 1);

  const int base = bp * NSAMP;
  int pos = start;
  unsigned mm = mask;
  while (mm && pos < NSAMP) {
    int j = __ffs(mm) - 1; mm &= mm - 1;
    ws_idx[base + pos] = k0 + j;
    ++pos;
  }
  if (lane >= total && lane < NSAMP) ws_idx[base + lane] = first;
}

// ---------------------------------------------------------------------------
// Merged prep: feats->bf16; weights -> bf16 B-layout [n][k]; gb = g*b+be.
// ---------------------------------------------------------------------------
__global__ __launch_bounds__(256) void prep_kernel(
    const float* __restrict__ feats, unsigned short* __restrict__ fbf,
    const float* __restrict__ w0, const float* __restrict__ w1,
    const float* __restrict__ w2, const float* __restrict__ w3,
    const float* __restrict__ b0, const float* __restrict__ g0, const float* __restrict__ be0,
    const float* __restrict__ b1, const float* __restrict__ g1, const float* __restrict__ be1,
    const float* __restrict__ b2, const float* __restrict__ g2, const float* __restrict__ be2,
    unsigned short* __restrict__ w0bt, unsigned short* __restrict__ w1bt,
    unsigned short* __restrict__ w2bt, float* __restrict__ w3p,
    float* __restrict__ gb0, float* __restrict__ gb1, float* __restrict__ gb2)
{
  if (blockIdx.x < 4096) {
    size_t i = ((size_t)blockIdx.x * 256 + threadIdx.x) * 8;
    float4 f0 = *(const float4*)(feats + i);
    float4 f1 = *(const float4*)(feats + i + 4);
    u16x8 o;
    o[0]=f2bf(f0.x); o[1]=f2bf(f0.y); o[2]=f2bf(f0.z); o[3]=f2bf(f0.w);
    o[4]=f2bf(f1.x); o[5]=f2bf(f1.y); o[6]=f2bf(f1.z); o[7]=f2bf(f1.w);
    *(u16x8*)(fbf + i) = o;
    return;
  }
  int id = (blockIdx.x - 4096) * 256 + threadIdx.x;
  if (id < 36864) {                       // w0bt [128][288]
    int n = id / 288, k = id - 288*n;
    float v = 0.f;
    if (k < 256) v = w0[(k+3)*128 + n];
    else if (k < 259) v = w0[(k-256)*128 + n];
    w0bt[id] = f2bf(v);
  } else if (id < 53248) {                // w1bt [128][128]
    int j = id - 36864; int n = j >> 7, k = j & 127;
    w1bt[j] = f2bf(w1[k*128 + n]);
  } else if (id < 69632) {                // w2bt [128][128]
    int j = id - 53248; int n = j >> 7, k = j & 127;
    w2bt[j] = f2bf(w2[k*128 + n]);
  } else if (id < 86016) {                // w3p [128][128] fp32, zero-padded
    int j = id - 69632; int k = j >> 7, c = j & 127;
    w3p[j] = (c < 119) ? w3[k*119 + c] : 0.f;
  } else if (id < 86144) {
    int c = id - 86016; gb0[c] = fmaf(g0[c], b0[c], be0[c]);
  } else if (id < 86272) {
    int c = id - 86144; gb1[c] = fmaf(g1[c], b1[c], be1[c]);
  } else if (id < 86400) {
    int c = id - 86272; gb2[c] = fmaf(g2[c], b2[c], be2[c]);
  }
}

// ---------------------------------------------------------------------------
// Kernel 2a: grouped MLP via 32x32x16 bf16 MFMA.
// 256-thread blocks = 4 independent waves, each doing 2 proposals with a
// private 8 KiB LDS act slice. K-loops unrolled x4 for load batching (MLP).
// ---------------------------------------------------------------------------
__global__ __launch_bounds__(256) void group_mlp_kernel(
    const float* __restrict__ xyz,
    const unsigned short* __restrict__ fbf,
    const unsigned short* __restrict__ w0bt,
    const unsigned short* __restrict__ w1bt,
    const unsigned short* __restrict__ w2bt,
    const float* __restrict__ g0, const float* __restrict__ gb0,
    const float* __restrict__ g1, const float* __restrict__ gb1,
    const float* __restrict__ g2, const float* __restrict__ gb2,
    const int* __restrict__ ws_idx,
    const float* __restrict__ onx,
    float* __restrict__ featws)
{
  __shared__ __align__(16) unsigned short act[4*4096];   // 32 KiB (8 KiB/wave)

  const int tid  = threadIdx.x;
  const int wave = tid >> 6;
  const int lane = tid & 63;
  const int s  = lane & 31;        // A row (sample) / B-D col bits (channel)
  const int h  = lane >> 5;        // K-half
  const int n0 = s;                // channel lane for B/D
  const int gw = blockIdx.x * 4 + wave;       // global wave id, 0..4095
  const int p  = gw * 2 + (s >> 4);           // this lane's A-row proposal
  const int b  = gw >> 7;                     // batch
  const int samp = s & 15;
  unsigned short* actw = act + wave * 4096;

  const int idx = ws_idx[p*16 + samp];
  const unsigned short* arow = fbf + ((size_t)(b*NPTS + idx) << 8);

  // gxyz A-fragment for kstep 16 (k=256..258 live in h==0 lanes)
  bf16x8 agx = (bf16x8){0,0,0,0,0,0,0,0};
  if (h == 0) {
    const float* pp = xyz + (size_t)(b*NPTS + idx)*3;
    agx[0] = (short)f2bf((pp[0] - onx[p*3+0]) * (1.0f/0.3f));
    agx[1] = (short)f2bf((pp[1] - onx[p*3+1]) * (1.0f/0.3f));
    agx[2] = (short)f2bf((pp[2] - onx[p*3+2]) * (1.0f/0.3f));
  }

  f32x16 acc[4];
#pragma unroll
  for (int nt = 0; nt < 4; ++nt) acc[nt] = (f32x16)(0.f);

  // ---- layer 0: K = 259 (ksteps 0..15 feats, 16 = gxyz; all-zero kstep 17 skipped)
#pragma unroll 4
  for (int ks = 0; ks < 16; ++ks) {
    bf16x8 a = *(const bf16x8*)(arow + ks*16 + h*8);
    const unsigned short* wp = w0bt + (size_t)n0*288 + ks*16 + h*8;
#pragma unroll
    for (int nt = 0; nt < 4; ++nt) {
      bf16x8 bb = *(const bf16x8*)(wp + (size_t)nt*32*288);
      acc[nt] = __builtin_amdgcn_mfma_f32_32x32x16_bf16(a, bb, acc[nt], 0, 0, 0);
    }
  }
  {
    const unsigned short* wp = w0bt + (size_t)n0*288 + 256 + h*8;
#pragma unroll
    for (int nt = 0; nt < 4; ++nt) {
      bf16x8 bb = *(const bf16x8*)(wp + (size_t)nt*32*288);
      acc[nt] = __builtin_amdgcn_mfma_f32_32x32x16_bf16(agx, bb, acc[nt], 0, 0, 0);
    }
  }
  // act0 -> LDS (relu(g*x+gb)), swizzled layout
#pragma unroll
  for (int nt = 0; nt < 4; ++nt) {
    int c = nt*32 + n0;
    int gch = c >> 3;
    float gg = g0[c], gv = gb0[c];
    int base = gch*256 + (c & 7);
#pragma unroll
    for (int r = 0; r < 16; ++r) {
      int srow = (r & 3) + 8*(r >> 2) + 4*h;
      float v = fmaxf(fmaf(gg, acc[nt][r], gv), 0.f);
      actw[base + ((srow + 2*gch) & 31)*8] = f2bf(v);
    }
  }
  __syncthreads();

  // ---- layer 1: K = 128
#pragma unroll
  for (int nt = 0; nt < 4; ++nt) acc[nt] = (f32x16)(0.f);
#pragma unroll 4
  for (int ks = 0; ks < 8; ++ks) {
    int g = ks*2 + h;
    bf16x8 a = *(const bf16x8*)(actw + g*256 + ((s + 2*g) & 31)*8);
    const unsigned short* wp = w1bt + (size_t)n0*128 + ks*16 + h*8;
#pragma unroll
    for (int nt = 0; nt < 4; ++nt) {
      bf16x8 bb = *(const bf16x8*)(wp + (size_t)nt*32*128);
      acc[nt] = __builtin_amdgcn_mfma_f32_32x32x16_bf16(a, bb, acc[nt], 0, 0, 0);
    }
  }
  __syncthreads();
#pragma unroll
  for (int nt = 0; nt < 4; ++nt) {
    int c = nt*32 + n0;
    int gch = c >> 3;
    float gg = g1[c], gv = gb1[c];
    int base = gch*256 + (c & 7);
#pragma unroll
    for (int r = 0; r < 16; ++r) {
      int srow = (r & 3) + 8*(r >> 2) + 4*h;
      float v = fmaxf(fmaf(gg, acc[nt][r], gv), 0.f);
      actw[base + ((srow + 2*gch) & 31)*8] = f2bf(v);
    }
  }
  __syncthreads();

  // ---- layer 2: K = 128, fused maxpool over each proposal's 16 samples
#pragma unroll
  for (int nt = 0; nt < 4; ++nt) acc[nt] = (f32x16)(0.f);
#pragma unroll 4
  for (int ks = 0; ks < 8; ++ks) {
    int g = ks*2 + h;
    bf16x8 a = *(const bf16x8*)(actw + g*256 + ((s + 2*g) & 31)*8);
    const unsigned short* wp = w2bt + (size_t)n0*128 + ks*16 + h*8;
#pragma unroll
    for (int nt = 0; nt < 4; ++nt) {
      bf16x8 bb = *(const bf16x8*)(wp + (size_t)nt*32*128);
      acc[nt] = __builtin_amdgcn_mfma_f32_32x32x16_bf16(a, bb, acc[nt], 0, 0, 0);
    }
  }
#pragma unroll
  for (int nt = 0; nt < 4; ++nt) {
    int c = nt*32 + n0;
    float gg = g2[c], gv = gb2[c];
    float m0 = 0.f, m1 = 0.f;   // relu => max >= 0
#pragma unroll
    for (int r = 0; r < 8; ++r)
      m0 = fmaxf(m0, fmaxf(fmaf(gg, acc[nt][r], gv), 0.f));       // rows 0..15  (prop lo)
#pragma unroll
    for (int r = 8; r < 16; ++r)
      m1 = fmaxf(m1, fmaxf(fmaf(gg, acc[nt][r], gv), 0.f));       // rows 16..31 (prop hi)
    m0 = fmaxf(m0, __shfl_xor(m0, 32));
    m1 = fmaxf(m1, __shfl_xor(m1, 32));
    float vout = h ? m1 : m0;
    featws[(size_t)(gw*2 + h)*128 + c] = vout;
  }
}

// ---------------------------------------------------------------------------
// Kernel 2b: FC head batched over proposals — fp32, 32 rows/block, 256 thr.
// ---------------------------------------------------------------------------
#define FCS 132
__global__ __launch_bounds__(256) void fc_head_kernel(
    const float* __restrict__ featws,
    const float* __restrict__ onx,
    const float* __restrict__ msize,
    const float* __restrict__ wf1, const float* __restrict__ bf1,
    const float* __restrict__ gf1, const float* __restrict__ bef1,
    const float* __restrict__ wf2, const float* __restrict__ bf2,
    const float* __restrict__ gf2, const float* __restrict__ bef2,
    const float* __restrict__ w3p, const float* __restrict__ b3,
    float* __restrict__ out)
{
  __shared__ float A[32*FCS];
  __shared__ float Bb[32*FCS];
  const int t = threadIdx.x;
  const int r = t >> 3;
  const int g = t & 7;
  const int row0 = blockIdx.x * 32;

#pragma unroll
  for (int i = 0; i < 16; ++i) {
    int id = t + 256*i;
    int rr = id >> 7, cc = id & 127;
    A[rr*FCS + cc] = featws[(size_t)(row0+rr)*128 + cc];
  }
  __syncthreads();

  float acc[16];
  // ---- FC1 (relu6): A -> Bb
#pragma unroll
  for (int i = 0; i < 16; ++i) acc[i] = 0.f;
#pragma unroll 4
  for (int k = 0; k < 128; ++k) {
    float a = A[r*FCS + k];
    const float4* wv = (const float4*)(wf1 + k*128 + g*16);
    float4 v0 = wv[0], v1 = wv[1], v2 = wv[2], v3 = wv[3];
    acc[0]  = fmaf(a, v0.x, acc[0]);  acc[1]  = fmaf(a, v0.y, acc[1]);
    acc[2]  = fmaf(a, v0.z, acc[2]);  acc[3]  = fmaf(a, v0.w, acc[3]);
    acc[4]  = fmaf(a, v1.x, acc[4]);  acc[5]  = fmaf(a, v1.y, acc[5]);
    acc[6]  = fmaf(a, v1.z, acc[6]);  acc[7]  = fmaf(a, v1.w, acc[7]);
    acc[8]  = fmaf(a, v2.x, acc[8]);  acc[9]  = fmaf(a, v2.y, acc[9]);
    acc[10] = fmaf(a, v2.z, acc[10]); acc[11] = fmaf(a, v2.w, acc[11]);
    acc[12] = fmaf(a, v3.x, acc[12]); acc[13] = fmaf(a, v3.y, acc[13]);
    acc[14] = fmaf(a, v3.z, acc[14]); acc[15] = fmaf(a, v3.w, acc[15]);
  }
#pragma unroll
  for (int i = 0; i < 16; ++i) {
    int c = g*16 + i;
    Bb[r*FCS + c] = fminf(fmaxf(fmaf(gf1[c], acc[i] + bf1[c], bef1[c]), 0.f), 6.f);
  }
  __syncthreads();

  // ---- FC2 (relu6): Bb -> A
#pragma unroll
  for (int i = 0; i < 16; ++i) acc[i] = 0.f;
#pragma unroll 4
  for (int k = 0; k < 128; ++k) {
    float a = Bb[r*FCS + k];
    const float4* wv = (const float4*)(wf2 + k*128 + g*16);
    float4 v0 = wv[0], v1 = wv[1], v2 = wv[2], v3 = wv[3];
    acc[0]  = fmaf(a, v0.x, acc[0]);  acc[1]  = fmaf(a, v0.y, acc[1]);
    acc[2]  = fmaf(a, v0.z, acc[2]);  acc[3]  = fmaf(a, v0.w, acc[3]);
    acc[4]  = fmaf(a, v1.x, acc[4]);  acc[5]  = fmaf(a, v1.y, acc[5]);
    acc[6]  = fmaf(a, v1.z, acc[6]);  acc[7]  = fmaf(a, v1.w, acc[7]);
    acc[8]  = fmaf(a, v2.x, acc[8]);  acc[9]  = fmaf(a, v2.y, acc[9]);
    acc[10] = fmaf(a, v2.z, acc[10]); acc[11] = fmaf(a, v2.w, acc[11]);
    acc[12] = fmaf(a, v3.x, acc[12]); acc[13] = fmaf(a, v3.y, acc[13]);
    acc[14] = fmaf(a, v3.z, acc[14]); acc[15] = fmaf(a, v3.w, acc[15]);
  }
#pragma unroll
  for (int i = 0; i < 16; ++i) {
    int c = g*16 + i;
    A[r*FCS + c] = fminf(fmaxf(fmaf(gf2[c], acc[i] + bf2[c], bef2[c]), 0.f), 6.f);
  }
  __syncthreads();

  // ---- FC3: A -> 119 outs, scatter with transforms
#pragma unroll
  for (int i = 0; i < 16; ++i) acc[i] = 0.f;
#pragma unroll 4
  for (int k = 0; k < 128; ++k) {
    float a = A[r*FCS + k];
    const float4* wv = (const float4*)(w3p + k*128 + g*16);
    float4 v0 = wv[0], v1 = wv[1], v2 = wv[2], v3 = wv[3];
    acc[0]  = fmaf(a, v0.x, acc[0]);  acc[1]  = fmaf(a, v0.y, acc[1]);
    acc[2]  = fmaf(a, v0.z, acc[2]);  acc[3]  = fmaf(a, v0.w, acc[3]);
    acc[4]  = fmaf(a, v1.x, acc[4]);  acc[5]  = fmaf(a, v1.y, acc[5]);
    acc[6]  = fmaf(a, v1.z, acc[6]);  acc[7]  = fmaf(a, v1.w, acc[7]);
    acc[8]  = fmaf(a, v2.x, acc[8]);  acc[9]  = fmaf(a, v2.y, acc[9]);
    acc[10] = fmaf(a, v2.z, acc[10]); acc[11] = fmaf(a, v2.w, acc[11]);
    acc[12] = fmaf(a, v3.x, acc[12]); acc[13] = fmaf(a, v3.y, acc[13]);
    acc[14] = fmaf(a, v3.z, acc[14]); acc[15] = fmaf(a, v3.w, acc[15]);
  }
  const int bp = row0 + r;
  const float HRC = (float)(3.14159265359 / 12.0);
#pragma unroll
  for (int i = 0; i < 16; ++i) {
    int c = g*16 + i;
    if (c >= 119) continue;
    float v = acc[i] + b3[c];
    if (c < 3) {
      out[O_CENTER + bp*3 + c] = onx[bp*3 + c] + v;
    } else if (c < 5) {
      out[O_OBJ + bp*2 + (c-3)] = v;
    } else if (c < 17) {
      out[O_HS + bp*12 + (c-5)] = v;
    } else if (c < 35) {
      out[O_SS + bp*18 + (c-17)] = v;
    } else if (c < 47) {
      int a2 = c - 35;
      out[O_HRN + bp*12 + a2] = v;
      out[O_HR  + bp*12 + a2] = v * HRC;
    } else if (c < 101) {
      int a2 = c - 47;
      out[O_SRN + bp*54 + a2] = v;
      out[O_SR  + bp*54 + a2] = v * msize[a2];
    } else {
      int a2 = c - 101;
      out[O_SEM + bp*18 + a2] = v;
    }
  }
}

// ---------------------------------------------------------------------------
extern "C" void kernel_launch(void* const* d_in, const int* in_sizes, int n_in,
                              void* d_out, int out_size, void* d_ws, size_t ws_size,
                              hipStream_t stream) {
  (void)in_sizes; (void)n_in; (void)out_size; (void)ws_size;
  const float* xyz   = (const float*)d_in[0];
  const float* feats = (const float*)d_in[1];
  const float* msize = (const float*)d_in[2];
  const float* w0  = (const float*)d_in[3];
  const float* b0  = (const float*)d_in[4];
  const float* g0  = (const float*)d_in[5];
  const float* be0 = (const float*)d_in[6];
  const float* w1  = (const float*)d_in[7];
  const float* b1  = (const float*)d_in[8];
  const float* g1  = (const float*)d_in[9];
  const float* be1 = (const float*)d_in[10];
  const float* w2  = (const float*)d_in[11];
  const float* b2  = (const float*)d_in[12];
  const float* g2  = (const float*)d_in[13];
  const float* be2 = (const float*)d_in[14];
  const float* wf1  = (const float*)d_in[15];
  const float* bf1  = (const float*)d_in[16];
  const float* gf1  = (const float*)d_in[17];
  const float* bef1 = (const float*)d_in[18];
  const float* wf2  = (const float*)d_in[19];
  const float* bf2  = (const float*)d_in[20];
  const float* gf2  = (const float*)d_in[21];
  const float* bef2 = (const float*)d_in[22];
  const float* w3 = (const float*)d_in[23];
  const float* b3 = (const float*)d_in[24];

  float* out = (float*)d_out;

  // workspace layout (bytes)
  char* wsb = (char*)d_ws;
  int*            ws_idx = (int*)           (wsb + 0);          //  512 KiB
  unsigned short* fbf    = (unsigned short*)(wsb + 524288);     // 16 MiB
  float*          featws = (float*)         (wsb + 17301504);   //  4 MiB
  unsigned short* w0bt   = (unsigned short*)(wsb + 21495808);   //  72 KiB
  unsigned short* w1bt   = (unsigned short*)(wsb + 21569536);   //  32 KiB
  unsigned short* w2bt   = (unsigned short*)(wsb + 21602304);   //  32 KiB
  float*          w3p    = (float*)         (wsb + 21635072);   //  64 KiB
  float*          gb0    = (float*)         (wsb + 21700608);   //  512 B
  float*          gb1    = (float*)         (wsb + 21701120);   //  512 B
  float*          gb2    = (float*)         (wsb + 21701632);   //  512 B

  fps_kernel<<<BATCH, 64, 0, stream>>>(xyz, out + O_NX, out + O_INDS);
  bq_kernel<<<(BATCH*NPROP)/4, 256, 0, stream>>>(xyz, out + O_NX, ws_idx);
  prep_kernel<<<4096 + 338, 256, 0, stream>>>(
      feats, fbf, w0, w1, w2, w3,
      b0, g0, be0, b1, g1, be1, b2, g2, be2,
      w0bt, w1bt, w2bt, w3p, gb0, gb1, gb2);
  group_mlp_kernel<<<(BATCH*NPROP)/8, 256, 0, stream>>>(
      xyz, fbf, w0bt, w1bt, w2bt,
      g0, gb0, g1, gb1, g2, gb2,
      ws_idx, out + O_NX, featws);
  fc_head_kernel<<<(BATCH*NPROP)/32, 256, 0, stream>>>(
      featws, out + O_NX, msize,
      wf1, bf1, gf1, bef1, wf2, bf2, gf2, bef2, w3p, b3, out);
}

// Round 7
// 413.683 us; speedup vs baseline: 1.0560x; 1.0560x over previous
//
#include <hip/hip_runtime.h>

#define BATCH 32
#define NPTS  1024
#define NFEAT 256
#define NPROP 256
#define NSAMP 16

// flat output offsets (floats), in reference tuple order
#define O_OBJ    0
#define O_CENTER 16384
#define O_HS     40960
#define O_HRN    139264
#define O_HR     237568
#define O_SS     335872
#define O_SRN    483328
#define O_SR     925696
#define O_SEM    1368064
#define O_NX     1515520
#define O_INDS   1540096

typedef __attribute__((ext_vector_type(8))) short bf16x8;
typedef __attribute__((ext_vector_type(8))) unsigned short u16x8;
typedef __attribute__((ext_vector_type(2))) float f32x2;
typedef __attribute__((ext_vector_type(16))) float f32x16;

__device__ __forceinline__ unsigned short f2bf(float f) {
  unsigned u = __builtin_bit_cast(unsigned, f);
  u += 0x7fffu + ((u >> 16) & 1u);   // RNE to bf16
  return (unsigned short)(u >> 16);
}

// single-op DPP f32 max step (ctrl pattern validated R3-R6)
template<int CTRL>
__device__ __forceinline__ float dpp_maxf(float v) {
  int x = __builtin_amdgcn_update_dpp(__builtin_bit_cast(int, v),
          __builtin_bit_cast(int, v), CTRL, 0xf, 0xf, false);
  return fmaxf(v, __builtin_bit_cast(float, x));
}

// ---------------------------------------------------------------------------
// Kernel 1: FPS (wave 0) + prep work (waves 1-3) in one 256-thread launch.
// FPS: 16 pts/lane in registers; per-iter: packed dist update, pk-max tree,
// 6x f32 DPP max, readlane, 16 ballots + SALU min-k scan. Barrier-free.
// Prep (spare waves, hidden under FPS): feats->bf16, weights->bf16 B-layout,
// gb = g*b+be, w3 pad. Exact fp32 FPS math (contract off) == numpy.
// ---------------------------------------------------------------------------
__global__ __launch_bounds__(256) void fps_prep_kernel(
    const float* __restrict__ xyz,
    const float* __restrict__ feats,
    const float* __restrict__ w0, const float* __restrict__ w1,
    const float* __restrict__ w2, const float* __restrict__ w3,
    const float* __restrict__ b0, const float* __restrict__ g0, const float* __restrict__ be0,
    const float* __restrict__ b1, const float* __restrict__ g1, const float* __restrict__ be1,
    const float* __restrict__ b2, const float* __restrict__ g2, const float* __restrict__ be2,
    unsigned short* __restrict__ fbf,
    unsigned short* __restrict__ w0bt, unsigned short* __restrict__ w1bt,
    unsigned short* __restrict__ w2bt, float* __restrict__ w3p,
    float* __restrict__ gb0, float* __restrict__ gb1, float* __restrict__ gb2,
    float* __restrict__ o_nx,
    float* __restrict__ o_inds)
{
#pragma clang fp contract(off)
  __shared__ float sxyz4[NPTS*4];          // padded [1024][4] for b128 broadcast
  __shared__ int   sInd[NPROP];

  const int tid = threadIdx.x;
  const int b   = blockIdx.x;

  if (tid < 64) {
    // ================= FPS: single wave, no barriers =================
    const int t = tid;
    const float* xb = xyz + b * NPTS * 3;
    for (int k = t; k < NPTS; k += 64) {
      sxyz4[k*4+0] = xb[k*3+0];
      sxyz4[k*4+1] = xb[k*3+1];
      sxyz4[k*4+2] = xb[k*3+2];
    }
    // wave-coherent LDS: compiler inserts lgkmcnt waits on dependency

    f32x2 px[8], py[8], pz[8], dd[8];
#pragma unroll
    for (int a = 0; a < 8; ++a) {
      int k0 = t + 128*a, k1 = k0 + 64;
      px[a] = (f32x2){sxyz4[k0*4+0], sxyz4[k1*4+0]};
      py[a] = (f32x2){sxyz4[k0*4+1], sxyz4[k1*4+1]};
      pz[a] = (f32x2){sxyz4[k0*4+2], sxyz4[k1*4+2]};
      dd[a] = (f32x2){1e10f, 1e10f};
    }

    int last = 0;
    for (int it = 1; it < NPROP; ++it) {
      float4 lp = *(const float4*)(sxyz4 + last*4);   // one ds_read_b128
      f32x2 vlx = (f32x2){lp.x, lp.x};
      f32x2 vly = (f32x2){lp.y, lp.y};
      f32x2 vlz = (f32x2){lp.z, lp.z};
#pragma unroll
      for (int a = 0; a < 8; ++a) {
        f32x2 dx = px[a] - vlx;
        f32x2 dy = py[a] - vly;
        f32x2 dz = pz[a] - vlz;
        f32x2 d  = dx*dx + dy*dy + dz*dz;   // contract off: mul,mul,mul,add,add
        dd[a] = __builtin_elementwise_min(dd[a], d);
      }
      // in-lane max: packed tree (depth 3) + final component max
      f32x2 m0 = __builtin_elementwise_max(dd[0], dd[1]);
      f32x2 m1 = __builtin_elementwise_max(dd[2], dd[3]);
      f32x2 m2 = __builtin_elementwise_max(dd[4], dd[5]);
      f32x2 m3 = __builtin_elementwise_max(dd[6], dd[7]);
      f32x2 mm = __builtin_elementwise_max(__builtin_elementwise_max(m0, m1),
                                           __builtin_elementwise_max(m2, m3));
      float m = fmaxf(mm[0], mm[1]);
      // cross-lane f32 max -> lane 63
      m = dpp_maxf<0x111>(m);   // row_shr:1
      m = dpp_maxf<0x112>(m);   // row_shr:2
      m = dpp_maxf<0x114>(m);   // row_shr:4
      m = dpp_maxf<0x118>(m);   // row_shr:8
      m = dpp_maxf<0x142>(m);   // row_bcast:15
      m = dpp_maxf<0x143>(m);   // row_bcast:31
      float gmax = __builtin_bit_cast(float,
          __builtin_amdgcn_readlane(__builtin_bit_cast(int, m), 63));
      // index recovery: 16 ballots (k = 64*j + lane, j = 2a+c) + SALU min-k scan
      unsigned long long msk[16];
#pragma unroll
      for (int a = 0; a < 8; ++a) {
        msk[2*a]   = __ballot(dd[a][0] == gmax);
        msk[2*a+1] = __ballot(dd[a][1] == gmax);
      }
      int nl = 0;
#pragma unroll
      for (int j = 15; j >= 0; --j) {
        unsigned long long mj = msk[j];
        if (mj) nl = j*64 + (int)__builtin_ctzll(mj);
      }
      last = nl;
      if (t == 0) sInd[it] = last;
    }
    if (t == 0) sInd[0] = 0;

    for (int s = t; s < NPROP; s += 64) {
      int ind = sInd[s];
      o_inds[b*NPROP + s] = (float)ind;
      float* nx = o_nx + (b*NPROP + s)*3;
      nx[0] = sxyz4[ind*4+0]; nx[1] = sxyz4[ind*4+1]; nx[2] = sxyz4[ind*4+2];
    }
  } else {
    // ================= prep: 3 spare waves x 32 blocks =================
    const int sp = b * 192 + (tid - 64);          // 0..6143
    // feats -> bf16 (8 floats per step)
    for (int i = sp; i < (BATCH*NPTS*NFEAT)/8; i += 6144) {
      size_t o = (size_t)i * 8;
      float4 f0 = *(const float4*)(feats + o);
      float4 f1 = *(const float4*)(feats + o + 4);
      u16x8 v;
      v[0]=f2bf(f0.x); v[1]=f2bf(f0.y); v[2]=f2bf(f0.z); v[3]=f2bf(f0.w);
      v[4]=f2bf(f1.x); v[5]=f2bf(f1.y); v[6]=f2bf(f1.z); v[7]=f2bf(f1.w);
      *(u16x8*)(fbf + o) = v;
    }
    // weights + gb
    for (int id = sp; id < 86400; id += 6144) {
      if (id < 36864) {                       // w0bt [128][288]
        int n = id / 288, k = id - 288*n;
        float v = 0.f;
        if (k < 256) v = w0[(k+3)*128 + n];
        else if (k < 259) v = w0[(k-256)*128 + n];
        w0bt[id] = f2bf(v);
      } else if (id < 53248) {                // w1bt [128][128]
        int j = id - 36864; int n = j >> 7, k = j & 127;
        w1bt[j] = f2bf(w1[k*128 + n]);
      } else if (id < 69632) {                // w2bt [128][128]
        int j = id - 53248; int n = j >> 7, k = j & 127;
        w2bt[j] = f2bf(w2[k*128 + n]);
      } else if (id < 86016) {                // w3p [128][128] fp32 zero-padded
        int j = id - 69632; int k = j >> 7, c = j & 127;
        w3p[j] = (c < 119) ? w3[k*119 + c] : 0.f;
      } else if (id < 86144) {
        int c = id - 86016; gb0[c] = fmaf(g0[c], b0[c], be0[c]);
      } else if (id < 86272) {
        int c = id - 86144; gb1[c] = fmaf(g1[c], b1[c], be1[c]);
      } else {
        int c = id - 86272; gb2[c] = fmaf(g2[c], b2[c], be2[c]);
      }
    }
  }
}

// ---------------------------------------------------------------------------
// Kernel 2a: ball query (in-wave) + grouped MLP via 32x32x16 bf16 MFMA.
// 256-thread blocks = 4 waves; each wave: BQ for its 2 proposals -> LDS,
// then the MLP with a private 8 KiB act slice.
// ---------------------------------------------------------------------------
__global__ __launch_bounds__(256) void group_mlp_kernel(
    const float* __restrict__ xyz,
    const unsigned short* __restrict__ fbf,
    const unsigned short* __restrict__ w0bt,
    const unsigned short* __restrict__ w1bt,
    const unsigned short* __restrict__ w2bt,
    const float* __restrict__ g0, const float* __restrict__ gb0,
    const float* __restrict__ g1, const float* __restrict__ gb1,
    const float* __restrict__ g2, const float* __restrict__ gb2,
    const float* __restrict__ onx,
    float* __restrict__ featws)
{
  __shared__ __align__(16) unsigned short act[4*4096];   // 32 KiB (8 KiB/wave)
  __shared__ int sIdxAll[4][32];                         // [wave][2 props x 16]

  const int tid  = threadIdx.x;
  const int wave = tid >> 6;
  const int lane = tid & 63;
  const int s  = lane & 31;        // A row (sample) / B-D col bits (channel)
  const int h  = lane >> 5;        // K-half
  const int n0 = s;                // channel lane for B/D
  const int gw = blockIdx.x * 4 + wave;       // global wave id, 0..4095
  const int p  = gw * 2 + (s >> 4);           // this lane's A-row proposal
  const int b  = gw >> 7;                     // batch
  const int samp = s & 15;
  unsigned short* actw = act + wave * 4096;
  int* sIdxW = sIdxAll[wave];

  // ---- in-wave ball query for this wave's 2 proposals (exact fp32 math)
  {
    const float* xb = xyz + b * NPTS * 3;
    const int k0 = lane * 16;
#pragma unroll
    for (int pi = 0; pi < 2; ++pi) {
      const int pp = gw*2 + pi;
      const float qx = onx[pp*3+0];
      const float qy = onx[pp*3+1];
      const float qz = onx[pp*3+2];
      unsigned mask = 0u;
#pragma unroll
      for (int j = 0; j < 16; ++j) {
        int k = k0 + j;
        float dx = __fsub_rn(qx, xb[k*3+0]);
        float dy = __fsub_rn(qy, xb[k*3+1]);
        float dz = __fsub_rn(qz, xb[k*3+2]);
        float d2 = __fadd_rn(__fadd_rn(__fmul_rn(dx,dx), __fmul_rn(dy,dy)), __fmul_rn(dz,dz));
        if (d2 < 0.09f) mask |= (1u << j);
      }
      int cnt  = __popc(mask);
      int incl = cnt;
#pragma unroll
      for (int ofs = 1; ofs < 64; ofs <<= 1) {
        int v = __shfl_up(incl, ofs);
        if (lane >= ofs) incl += v;
      }
      int start = incl - cnt;
      int total = __shfl(incl, 63);
      int fc = mask ? (k0 + __ffs(mask) - 1) : 0x7fffffff;
#pragma unroll
      for (int m = 32; m >= 1; m >>= 1) fc = min(fc, __shfl_xor(fc, m));
      int first = (total > 0) ? fc : (NPTS - 1);
      int* dst = sIdxW + pi*16;
      if (lane >= total && lane < NSAMP) dst[lane] = first;
      int pos = start;
      unsigned mm = mask;
      while (mm && pos < NSAMP) {
        int j = __ffs(mm) - 1; mm &= mm - 1;
        dst[pos] = k0 + j;
        ++pos;
      }
    }
  }
  __syncthreads();   // all 4 waves reach this; also orders sIdx writes

  const int idx = sIdxW[(s>>4)*16 + samp];
  const unsigned short* arow = fbf + ((size_t)(b*NPTS + idx) << 8);

  // gxyz A-fragment for kstep 16 (k=256..258 live in h==0 lanes)
  bf16x8 agx = (bf16x8){0,0,0,0,0,0,0,0};
  if (h == 0) {
    const float* pp = xyz + (size_t)(b*NPTS + idx)*3;
    agx[0] = (short)f2bf((pp[0] - onx[p*3+0]) * (1.0f/0.3f));
    agx[1] = (short)f2bf((pp[1] - onx[p*3+1]) * (1.0f/0.3f));
    agx[2] = (short)f2bf((pp[2] - onx[p*3+2]) * (1.0f/0.3f));
  }

  f32x16 acc[4];
#pragma unroll
  for (int nt = 0; nt < 4; ++nt) acc[nt] = (f32x16)(0.f);

  // ---- layer 0: K = 259 (ksteps 0..15 feats, 16 = gxyz; zero kstep skipped)
#pragma unroll 4
  for (int ks = 0; ks < 16; ++ks) {
    bf16x8 a = *(const bf16x8*)(arow + ks*16 + h*8);
    const unsigned short* wp = w0bt + (size_t)n0*288 + ks*16 + h*8;
#pragma unroll
    for (int nt = 0; nt < 4; ++nt) {
      bf16x8 bb = *(const bf16x8*)(wp + (size_t)nt*32*288);
      acc[nt] = __builtin_amdgcn_mfma_f32_32x32x16_bf16(a, bb, acc[nt], 0, 0, 0);
    }
  }
  {
    const unsigned short* wp = w0bt + (size_t)n0*288 + 256 + h*8;
#pragma unroll
    for (int nt = 0; nt < 4; ++nt) {
      bf16x8 bb = *(const bf16x8*)(wp + (size_t)nt*32*288);
      acc[nt] = __builtin_amdgcn_mfma_f32_32x32x16_bf16(agx, bb, acc[nt], 0, 0, 0);
    }
  }
  // act0 -> LDS (relu(g*x+gb)), swizzled layout
#pragma unroll
  for (int nt = 0; nt < 4; ++nt) {
    int c = nt*32 + n0;
    int gch = c >> 3;
    float gg = g0[c], gv = gb0[c];
    int base = gch*256 + (c & 7);
#pragma unroll
    for (int r = 0; r < 16; ++r) {
      int srow = (r & 3) + 8*(r >> 2) + 4*h;
      float v = fmaxf(fmaf(gg, acc[nt][r], gv), 0.f);
      actw[base + ((srow + 2*gch) & 31)*8] = f2bf(v);
    }
  }
  __syncthreads();

  // ---- layer 1: K = 128
#pragma unroll
  for (int nt = 0; nt < 4; ++nt) acc[nt] = (f32x16)(0.f);
#pragma unroll 4
  for (int ks = 0; ks < 8; ++ks) {
    int g = ks*2 + h;
    bf16x8 a = *(const bf16x8*)(actw + g*256 + ((s + 2*g) & 31)*8);
    const unsigned short* wp = w1bt + (size_t)n0*128 + ks*16 + h*8;
#pragma unroll
    for (int nt = 0; nt < 4; ++nt) {
      bf16x8 bb = *(const bf16x8*)(wp + (size_t)nt*32*128);
      acc[nt] = __builtin_amdgcn_mfma_f32_32x32x16_bf16(a, bb, acc[nt], 0, 0, 0);
    }
  }
  __syncthreads();
#pragma unroll
  for (int nt = 0; nt < 4; ++nt) {
    int c = nt*32 + n0;
    int gch = c >> 3;
    float gg = g1[c], gv = gb1[c];
    int base = gch*256 + (c & 7);
#pragma unroll
    for (int r = 0; r < 16; ++r) {
      int srow = (r & 3) + 8*(r >> 2) + 4*h;
      float v = fmaxf(fmaf(gg, acc[nt][r], gv), 0.f);
      actw[base + ((srow + 2*gch) & 31)*8] = f2bf(v);
    }
  }
  __syncthreads();

  // ---- layer 2: K = 128, fused maxpool over each proposal's 16 samples
#pragma unroll
  for (int nt = 0; nt < 4; ++nt) acc[nt] = (f32x16)(0.f);
#pragma unroll 4
  for (int ks = 0; ks < 8; ++ks) {
    int g = ks*2 + h;
    bf16x8 a = *(const bf16x8*)(actw + g*256 + ((s + 2*g) & 31)*8);
    const unsigned short* wp = w2bt + (size_t)n0*128 + ks*16 + h*8;
#pragma unroll
    for (int nt = 0; nt < 4; ++nt) {
      bf16x8 bb = *(const bf16x8*)(wp + (size_t)nt*32*128);
      acc[nt] = __builtin_amdgcn_mfma_f32_32x32x16_bf16(a, bb, acc[nt], 0, 0, 0);
    }
  }
#pragma unroll
  for (int nt = 0; nt < 4; ++nt) {
    int c = nt*32 + n0;
    float gg = g2[c], gv = gb2[c];
    float m0 = 0.f, m1 = 0.f;   // relu => max >= 0
#pragma unroll
    for (int r = 0; r < 8; ++r)
      m0 = fmaxf(m0, fmaxf(fmaf(gg, acc[nt][r], gv), 0.f));       // rows 0..15  (prop lo)
#pragma unroll
    for (int r = 8; r < 16; ++r)
      m1 = fmaxf(m1, fmaxf(fmaf(gg, acc[nt][r], gv), 0.f));       // rows 16..31 (prop hi)
    m0 = fmaxf(m0, __shfl_xor(m0, 32));
    m1 = fmaxf(m1, __shfl_xor(m1, 32));
    float vout = h ? m1 : m0;
    featws[(size_t)(gw*2 + h)*128 + c] = vout;
  }
}

// ---------------------------------------------------------------------------
// Kernel 2b: FC head batched over proposals — fp32, 32 rows/block, 256 thr.
// ---------------------------------------------------------------------------
#define FCS 132
__global__ __launch_bounds__(256) void fc_head_kernel(
    const float* __restrict__ featws,
    const float* __restrict__ onx,
    const float* __restrict__ msize,
    const float* __restrict__ wf1, const float* __restrict__ bf1,
    const float* __restrict__ gf1, const float* __restrict__ bef1,
    const float* __restrict__ wf2, const float* __restrict__ bf2,
    const float* __restrict__ gf2, const float* __restrict__ bef2,
    const float* __restrict__ w3p, const float* __restrict__ b3,
    float* __restrict__ out)
{
  __shared__ float A[32*FCS];
  __shared__ float Bb[32*FCS];
  const int t = threadIdx.x;
  const int r = t >> 3;
  const int g = t & 7;
  const int row0 = blockIdx.x * 32;

#pragma unroll
  for (int i = 0; i < 16; ++i) {
    int id = t + 256*i;
    int rr = id >> 7, cc = id & 127;
    A[rr*FCS + cc] = featws[(size_t)(row0+rr)*128 + cc];
  }
  __syncthreads();

  float acc[16];
  // ---- FC1 (relu6): A -> Bb
#pragma unroll
  for (int i = 0; i < 16; ++i) acc[i] = 0.f;
#pragma unroll 4
  for (int k = 0; k < 128; ++k) {
    float a = A[r*FCS + k];
    const float4* wv = (const float4*)(wf1 + k*128 + g*16);
    float4 v0 = wv[0], v1 = wv[1], v2 = wv[2], v3 = wv[3];
    acc[0]  = fmaf(a, v0.x, acc[0]);  acc[1]  = fmaf(a, v0.y, acc[1]);
    acc[2]  = fmaf(a, v0.z, acc[2]);  acc[3]  = fmaf(a, v0.w, acc[3]);
    acc[4]  = fmaf(a, v1.x, acc[4]);  acc[5]  = fmaf(a, v1.y, acc[5]);
    acc[6]  = fmaf(a, v1.z, acc[6]);  acc[7]  = fmaf(a, v1.w, acc[7]);
    acc[8]  = fmaf(a, v2.x, acc[8]);  acc[9]  = fmaf(a, v2.y, acc[9]);
    acc[10] = fmaf(a, v2.z, acc[10]); acc[11] = fmaf(a, v2.w, acc[11]);
    acc[12] = fmaf(a, v3.x, acc[12]); acc[13] = fmaf(a, v3.y, acc[13]);
    acc[14] = fmaf(a, v3.z, acc[14]); acc[15] = fmaf(a, v3.w, acc[15]);
  }
#pragma unroll
  for (int i = 0; i < 16; ++i) {
    int c = g*16 + i;
    Bb[r*FCS + c] = fminf(fmaxf(fmaf(gf1[c], acc[i] + bf1[c], bef1[c]), 0.f), 6.f);
  }
  __syncthreads();

  // ---- FC2 (relu6): Bb -> A
#pragma unroll
  for (int i = 0; i < 16; ++i) acc[i] = 0.f;
#pragma unroll 4
  for (int k = 0; k < 128; ++k) {
    float a = Bb[r*FCS + k];
    const float4* wv = (const float4*)(wf2 + k*128 + g*16);
    float4 v0 = wv[0], v1 = wv[1], v2 = wv[2], v3 = wv[3];
    acc[0]  = fmaf(a, v0.x, acc[0]);  acc[1]  = fmaf(a, v0.y, acc[1]);
    acc[2]  = fmaf(a, v0.z, acc[2]);  acc[3]  = fmaf(a, v0.w, acc[3]);
    acc[4]  = fmaf(a, v1.x, acc[4]);  acc[5]  = fmaf(a, v1.y, acc[5]);
    acc[6]  = fmaf(a, v1.z, acc[6]);  acc[7]  = fmaf(a, v1.w, acc[7]);
    acc[8]  = fmaf(a, v2.x, acc[8]);  acc[9]  = fmaf(a, v2.y, acc[9]);
    acc[10] = fmaf(a, v2.z, acc[10]); acc[11] = fmaf(a, v2.w, acc[11]);
    acc[12] = fmaf(a, v3.x, acc[12]); acc[13] = fmaf(a, v3.y, acc[13]);
    acc[14] = fmaf(a, v3.z, acc[14]); acc[15] = fmaf(a, v3.w, acc[15]);
  }
#pragma unroll
  for (int i = 0; i < 16; ++i) {
    int c = g*16 + i;
    A[r*FCS + c] = fminf(fmaxf(fmaf(gf2[c], acc[i] + bf2[c], bef2[c]), 0.f), 6.f);
  }
  __syncthreads();

  // ---- FC3: A -> 119 outs, scatter with transforms
#pragma unroll
  for (int i = 0; i < 16; ++i) acc[i] = 0.f;
#pragma unroll 4
  for (int k = 0; k < 128; ++k) {
    float a = A[r*FCS + k];
    const float4* wv = (const float4*)(w3p + k*128 + g*16);
    float4 v0 = wv[0], v1 = wv[1], v2 = wv[2], v3 = wv[3];
    acc[0]  = fmaf(a, v0.x, acc[0]);  acc[1]  = fmaf(a, v0.y, acc[1]);
    acc[2]  = fmaf(a, v0.z, acc[2]);  acc[3]  = fmaf(a, v0.w, acc[3]);
    acc[4]  = fmaf(a, v1.x, acc[4]);  acc[5]  = fmaf(a, v1.y, acc[5]);
    acc[6]  = fmaf(a, v1.z, acc[6]);  acc[7]  = fmaf(a, v1.w, acc[7]);
    acc[8]  = fmaf(a, v2.x, acc[8]);  acc[9]  = fmaf(a, v2.y, acc[9]);
    acc[10] = fmaf(a, v2.z, acc[10]); acc[11] = fmaf(a, v2.w, acc[11]);
    acc[12] = fmaf(a, v3.x, acc[12]); acc[13] = fmaf(a, v3.y, acc[13]);
    acc[14] = fmaf(a, v3.z, acc[14]); acc[15] = fmaf(a, v3.w, acc[15]);
  }
  const int bp = row0 + r;
  const float HRC = (float)(3.14159265359 / 12.0);
#pragma unroll
  for (int i = 0; i < 16; ++i) {
    int c = g*16 + i;
    if (c >= 119) continue;
    float v = acc[i] + b3[c];
    if (c < 3) {
      out[O_CENTER + bp*3 + c] = onx[bp*3 + c] + v;
    } else if (c < 5) {
      out[O_OBJ + bp*2 + (c-3)] = v;
    } else if (c < 17) {
      out[O_HS + bp*12 + (c-5)] = v;
    } else if (c < 35) {
      out[O_SS + bp*18 + (c-17)] = v;
    } else if (c < 47) {
      int a2 = c - 35;
      out[O_HRN + bp*12 + a2] = v;
      out[O_HR  + bp*12 + a2] = v * HRC;
    } else if (c < 101) {
      int a2 = c - 47;
      out[O_SRN + bp*54 + a2] = v;
      out[O_SR  + bp*54 + a2] = v * msize[a2];
    } else {
      int a2 = c - 101;
      out[O_SEM + bp*18 + a2] = v;
    }
  }
}

// ---------------------------------------------------------------------------
extern "C" void kernel_launch(void* const* d_in, const int* in_sizes, int n_in,
                              void* d_out, int out_size, void* d_ws, size_t ws_size,
                              hipStream_t stream) {
  (void)in_sizes; (void)n_in; (void)out_size; (void)ws_size;
  const float* xyz   = (const float*)d_in[0];
  const float* feats = (const float*)d_in[1];
  const float* msize = (const float*)d_in[2];
  const float* w0  = (const float*)d_in[3];
  const float* b0  = (const float*)d_in[4];
  const float* g0  = (const float*)d_in[5];
  const float* be0 = (const float*)d_in[6];
  const float* w1  = (const float*)d_in[7];
  const float* b1  = (const float*)d_in[8];
  const float* g1  = (const float*)d_in[9];
  const float* be1 = (const float*)d_in[10];
  const float* w2  = (const float*)d_in[11];
  const float* b2  = (const float*)d_in[12];
  const float* g2  = (const float*)d_in[13];
  const float* be2 = (const float*)d_in[14];
  const float* wf1  = (const float*)d_in[15];
  const float* bf1  = (const float*)d_in[16];
  const float* gf1  = (const float*)d_in[17];
  const float* bef1 = (const float*)d_in[18];
  const float* wf2  = (const float*)d_in[19];
  const float* bf2  = (const float*)d_in[20];
  const float* gf2  = (const float*)d_in[21];
  const float* bef2 = (const float*)d_in[22];
  const float* w3 = (const float*)d_in[23];
  const float* b3 = (const float*)d_in[24];

  float* out = (float*)d_out;

  // workspace layout (bytes)
  char* wsb = (char*)d_ws;
  unsigned short* fbf    = (unsigned short*)(wsb + 524288);     // 16 MiB
  float*          featws = (float*)         (wsb + 17301504);   //  4 MiB
  unsigned short* w0bt   = (unsigned short*)(wsb + 21495808);   //  72 KiB
  unsigned short* w1bt   = (unsigned short*)(wsb + 21569536);   //  32 KiB
  unsigned short* w2bt   = (unsigned short*)(wsb + 21602304);   //  32 KiB
  float*          w3p    = (float*)         (wsb + 21635072);   //  64 KiB
  float*          gb0    = (float*)         (wsb + 21700608);   //  512 B
  float*          gb1    = (float*)         (wsb + 21701120);   //  512 B
  float*          gb2    = (float*)         (wsb + 21701632);   //  512 B

  fps_prep_kernel<<<BATCH, 256, 0, stream>>>(
      xyz, feats, w0, w1, w2, w3,
      b0, g0, be0, b1, g1, be1, b2, g2, be2,
      fbf, w0bt, w1bt, w2bt, w3p, gb0, gb1, gb2,
      out + O_NX, out + O_INDS);
  group_mlp_kernel<<<(BATCH*NPROP)/8, 256, 0, stream>>>(
      xyz, fbf, w0bt, w1bt, w2bt,
      g0, gb0, g1, gb1, g2, gb2,
      out + O_NX, featws);
  fc_head_kernel<<<(BATCH*NPROP)/32, 256, 0, stream>>>(
      featws, out + O_NX, msize,
      wf1, bf1, gf1, bef1, wf2, bf2, gf2, bef2, w3p, b3, out);
}